// Round 14
// baseline (730.010 us; speedup 1.0000x reference)
//
#include <hip/hip_runtime.h>
#include <hip/hip_cooperative_groups.h>
namespace cg = cooperative_groups;

#define N_NODES 10000
#define N_EDGES 320000
#define IN_F    512
#define H1F     256
#define H2F     64

typedef __attribute__((ext_vector_type(8)))  short short8;   // 8 x bf16 (4 VGPRs)
typedef __attribute__((ext_vector_type(16))) float f32x16;   // MFMA 32x32 accumulator

__device__ __forceinline__ unsigned short f2bf(float f) {
    union { float fl; unsigned int i; } v; v.fl = f;
    unsigned int x = v.i;
    return (unsigned short)((x + 0x7fffu + ((x >> 16) & 1u)) >> 16);
}
__device__ __forceinline__ float bf2f(unsigned short u) {
    union { unsigned int i; float f; } v; v.i = ((unsigned int)u) << 16; return v.f;
}
// dict order (ew,src,dst): c0=float weight, int-reinterp never in [0,N_NODES)
// (only denormals); alpha order (dst,src,ew): c0=dst always is.
__device__ __forceinline__ bool edge_is_alpha(int a0) {
    return (unsigned)a0 < N_NODES;
}

// ---------- cooperative CSR build: zero -> hist -> scan -> bucket, 1 launch ----------
__global__ void k_csr(const int* __restrict__ c0, const int* __restrict__ c1,
                      const int* __restrict__ c2, const float* __restrict__ c0f,
                      const float* __restrict__ c2f,
                      int* __restrict__ deg, int* __restrict__ off,
                      int* __restrict__ cursor, int2* __restrict__ ep,
                      int* __restrict__ partial, int* __restrict__ pex) {
    cg::grid_group grid = cg::this_grid();
    int b = blockIdx.x, t = threadIdx.x;
    int gtid = b * 256 + t, gsz = gridDim.x * 256;
    __shared__ int incl[64];
    const int CH = 40;                           // nodes per block (256*40 >= 10000)
    // P0: zero deg
    for (int i = gtid; i < N_NODES; i += gsz) deg[i] = 0;
    grid.sync();
    // P1: histogram
    for (int e = gtid; e < N_EDGES; e += gsz) {
        int a0 = c0[e];
        int dst = edge_is_alpha(a0) ? a0 : c2[e];
        if ((unsigned)dst < N_NODES) atomicAdd(&deg[dst], 1);
    }
    grid.sync();
    // P2a: per-block inclusive scan of its chunk (wave 0)
    if (t < 64) {
        int i = b * CH + t;
        int v = (t < CH && i < N_NODES) ? deg[i] : 0;
        #pragma unroll
        for (int o2 = 1; o2 < 64; o2 <<= 1) {
            int u = __shfl_up(v, o2, 64);
            if (t >= o2) v += u;
        }
        incl[t] = v;
        if (t == 63) partial[b] = v;
    }
    grid.sync();
    // P2b: block 0, wave 0: exclusive scan of 256 block partials
    if (b == 0 && t < 64) {
        int i4 = t * 4;
        int p0 = partial[i4], p1 = partial[i4+1], p2 = partial[i4+2], p3 = partial[i4+3];
        int s0 = p0, s1 = s0 + p1, s2 = s1 + p2, s3 = s2 + p3;
        int v = s3;
        #pragma unroll
        for (int o2 = 1; o2 < 64; o2 <<= 1) {
            int u = __shfl_up(v, o2, 64);
            if (t >= o2) v += u;
        }
        int ebase = v - s3;
        pex[i4] = ebase; pex[i4+1] = ebase + s0; pex[i4+2] = ebase + s1; pex[i4+3] = ebase + s2;
    }
    grid.sync();
    // P2c: write off/cursor
    if (t < CH) {
        int i = b * CH + t;
        if (i < N_NODES) {
            int val = pex[b] + (t ? incl[t-1] : 0);
            off[i] = val; cursor[i] = val;
            if (i == N_NODES - 1) off[N_NODES] = pex[b] + incl[t];
        }
    }
    grid.sync();
    // P3: bucket (packed (src, w))
    for (int e = gtid; e < N_EDGES; e += gsz) {
        int a0 = c0[e];
        bool alpha = edge_is_alpha(a0);
        int src = c1[e];
        int dst = alpha ? a0 : c2[e];
        float w = alpha ? c2f[e] : c0f[e];
        if ((unsigned)src >= N_NODES || (unsigned)dst >= N_NODES) continue;
        int p = atomicAdd(&cursor[dst], 1);
        ep[p] = make_int2(src, __float_as_int(w));
    }
}

// ---------- weight transpose to bf16: W1t[f][k], W2t[f][k] ----------
__global__ __launch_bounds__(256) void k_wtrans(const float* __restrict__ W1,
                                                const float* __restrict__ W2,
                                                unsigned short* __restrict__ W1t,
                                                unsigned short* __restrict__ W2t) {
    int idx = blockIdx.x * 256 + threadIdx.x;
    if (idx < IN_F * H1F) {
        int k = idx / H1F, f = idx % H1F;          // coalesced read
        W1t[(size_t)f * IN_F + k] = f2bf(W1[idx]);
    }
    int idx2 = idx - IN_F * H1F;
    if (idx2 >= 0 && idx2 < H1F * H2F) {
        int k = idx2 / H2F, f = idx2 % H2F;
        W2t[(size_t)f * H1F + k] = f2bf(W2[idx2]);
    }
}

// ---------- MFMA GEMM1: sup1b[10000,256](bf16) = x @ W1 ----------
// Block: 64 nodes x 256 feats, 4 waves (wave = 64-f slice). A staged bf16 in LDS
// fragment-major [half][m][8]; B read directly from L2-hot W1t rows.
__global__ __launch_bounds__(256) void k_gemm1m(const float* __restrict__ x,
                                                const unsigned short* __restrict__ W1t,
                                                unsigned short* __restrict__ sup1b) {
    __shared__ unsigned short As[2 * 64 * 8];
    int t = threadIdx.x;
    int nb = blockIdx.x * 64;
    int wave = t >> 6, lane = t & 63;
    int half = lane >> 5, r = lane & 31;
    int fb = wave * 64;
    int srow = t >> 2, skk = (t & 3) * 4;
    unsigned short* sdst = &As[(((skk >> 3) * 64 + srow) * 8) + (skk & 7)];
    const float* xrow = x + (size_t)(nb + srow) * IN_F + skk;
    bool svalid = (nb + srow) < N_NODES;

    f32x16 acc[2][2];
    #pragma unroll
    for (int mi = 0; mi < 2; mi++)
        #pragma unroll
        for (int ni = 0; ni < 2; ni++)
            #pragma unroll
            for (int i = 0; i < 16; i++) acc[mi][ni][i] = 0.f;

    for (int k0 = 0; k0 < IN_F; k0 += 16) {
        __syncthreads();
        float4 v = svalid ? *(const float4*)(xrow + k0) : make_float4(0.f, 0.f, 0.f, 0.f);
        ushort4 u; u.x = f2bf(v.x); u.y = f2bf(v.y); u.z = f2bf(v.z); u.w = f2bf(v.w);
        *(ushort4*)sdst = u;
        __syncthreads();
        short8 a0 = *(const short8*)&As[(half * 64 + r) * 8];
        short8 a1 = *(const short8*)&As[(half * 64 + 32 + r) * 8];
        short8 b0 = *(const short8*)&W1t[(size_t)(fb + r) * IN_F + k0 + half * 8];
        short8 b1 = *(const short8*)&W1t[(size_t)(fb + 32 + r) * IN_F + k0 + half * 8];
        acc[0][0] = __builtin_amdgcn_mfma_f32_32x32x16_bf16(a0, b0, acc[0][0], 0, 0, 0);
        acc[0][1] = __builtin_amdgcn_mfma_f32_32x32x16_bf16(a0, b1, acc[0][1], 0, 0, 0);
        acc[1][0] = __builtin_amdgcn_mfma_f32_32x32x16_bf16(a1, b0, acc[1][0], 0, 0, 0);
        acc[1][1] = __builtin_amdgcn_mfma_f32_32x32x16_bf16(a1, b1, acc[1][1], 0, 0, 0);
    }
    #pragma unroll
    for (int mi = 0; mi < 2; mi++) {
        #pragma unroll
        for (int rg = 0; rg < 16; rg++) {
            int row = nb + mi * 32 + (rg & 3) + 8 * (rg >> 2) + 4 * half;
            if (row < N_NODES) {
                #pragma unroll
                for (int ni = 0; ni < 2; ni++) {
                    int col = fb + ni * 32 + r;
                    sup1b[(size_t)row * H1F + col] = f2bf(acc[mi][ni][rg]);
                }
            }
        }
    }
}

// ---------- MFMA GEMM2: sup2[10000,64](fp32) = h1 @ W2 ----------
__global__ __launch_bounds__(256) void k_gemm2m(const float* __restrict__ h1,
                                                const unsigned short* __restrict__ W2t,
                                                float* __restrict__ sup2) {
    __shared__ unsigned short As[2 * 64 * 8];
    int t = threadIdx.x;
    int nb = blockIdx.x * 64;
    int wave = t >> 6, lane = t & 63;
    int half = lane >> 5, r = lane & 31;
    int mi = wave >> 1, ni = wave & 1;
    int srow = t >> 2, skk = (t & 3) * 4;
    unsigned short* sdst = &As[(((skk >> 3) * 64 + srow) * 8) + (skk & 7)];
    const float* hrow = h1 + (size_t)(nb + srow) * H1F + skk;
    bool svalid = (nb + srow) < N_NODES;

    f32x16 acc;
    #pragma unroll
    for (int i = 0; i < 16; i++) acc[i] = 0.f;

    for (int k0 = 0; k0 < H1F; k0 += 16) {
        __syncthreads();
        float4 v = svalid ? *(const float4*)(hrow + k0) : make_float4(0.f, 0.f, 0.f, 0.f);
        ushort4 u; u.x = f2bf(v.x); u.y = f2bf(v.y); u.z = f2bf(v.z); u.w = f2bf(v.w);
        *(ushort4*)sdst = u;
        __syncthreads();
        short8 a = *(const short8*)&As[(half * 64 + mi * 32 + r) * 8];
        short8 b = *(const short8*)&W2t[(size_t)(ni * 32 + r) * H1F + k0 + half * 8];
        acc = __builtin_amdgcn_mfma_f32_32x32x16_bf16(a, b, acc, 0, 0, 0);
    }
    #pragma unroll
    for (int rg = 0; rg < 16; rg++) {
        int row = nb + mi * 32 + (rg & 3) + 8 * (rg >> 2) + 4 * half;
        int col = ni * 32 + r;
        if (row < N_NODES) sup2[(size_t)row * H2F + col] = acc[rg];
    }
}

// ---------- agg1: LDS-staged edges, 4-way unrolled gathers ----------
__global__ __launch_bounds__(256) void k_agg1(const unsigned short* __restrict__ sup1b,
                                              const int* __restrict__ off,
                                              const int2* __restrict__ ep,
                                              const float* __restrict__ b1,
                                              float* __restrict__ h1) {
    __shared__ int2 eds[256];
    int node = blockIdx.x;
    int f = threadIdx.x;
    int s = off[node], e = off[node + 1];
    float a0 = 0.f, a1 = 0.f, a2 = 0.f, a3 = 0.f;
    for (int base = s; base < e; base += 256) {
        int n = e - base; if (n > 256) n = 256;
        __syncthreads();
        if (f < n) eds[f] = ep[base + f];
        __syncthreads();
        int j = 0;
        for (; j + 4 <= n; j += 4) {
            int2 e0 = eds[j], e1 = eds[j+1], e2 = eds[j+2], e3 = eds[j+3];
            a0 += __int_as_float(e0.y) * bf2f(sup1b[(size_t)e0.x * H1F + f]);
            a1 += __int_as_float(e1.y) * bf2f(sup1b[(size_t)e1.x * H1F + f]);
            a2 += __int_as_float(e2.y) * bf2f(sup1b[(size_t)e2.x * H1F + f]);
            a3 += __int_as_float(e3.y) * bf2f(sup1b[(size_t)e3.x * H1F + f]);
        }
        for (; j < n; ++j) {
            int2 e0 = eds[j];
            a0 += __int_as_float(e0.y) * bf2f(sup1b[(size_t)e0.x * H1F + f]);
        }
    }
    float acc = (a0 + a1) + (a2 + a3);
    h1[(size_t)node * H1F + f] = fmaxf(acc + b1[f], 0.f);
}

// ---------- agg2: LDS-staged, unrolled; z fp32 (d_out) + bf16 zb (ws) ----------
__global__ __launch_bounds__(64) void k_agg2(const float* __restrict__ sup2,
                                             const int* __restrict__ off,
                                             const int2* __restrict__ ep,
                                             const float* __restrict__ b2,
                                             float* __restrict__ zout,
                                             unsigned short* __restrict__ zb) {
    __shared__ int2 eds[64];
    int node = blockIdx.x;
    int f = threadIdx.x;
    int s = off[node], e = off[node + 1];
    float a0 = 0.f, a1 = 0.f, a2 = 0.f, a3 = 0.f;
    for (int base = s; base < e; base += 64) {
        int n = e - base; if (n > 64) n = 64;
        __syncthreads();
        if (f < n) eds[f] = ep[base + f];
        __syncthreads();
        int j = 0;
        for (; j + 4 <= n; j += 4) {
            int2 e0 = eds[j], e1 = eds[j+1], e2 = eds[j+2], e3 = eds[j+3];
            a0 += __int_as_float(e0.y) * sup2[(size_t)e0.x * H2F + f];
            a1 += __int_as_float(e1.y) * sup2[(size_t)e1.x * H2F + f];
            a2 += __int_as_float(e2.y) * sup2[(size_t)e2.x * H2F + f];
            a3 += __int_as_float(e3.y) * sup2[(size_t)e3.x * H2F + f];
        }
        for (; j < n; ++j) {
            int2 e0 = eds[j];
            a0 += __int_as_float(e0.y) * sup2[(size_t)e0.x * H2F + f];
        }
    }
    float acc = (a0 + a1) + (a2 + a3);
    acc = fmaxf(acc + b2[f], 0.f);
    zout[(size_t)node * H2F + f] = acc;
    zb[(size_t)node * H2F + f] = f2bf(acc);
}

// ---------- decoder: recon = sigmoid(zb @ zb^T) via bf16 MFMA 32x32x16 ----------
__global__ __launch_bounds__(256) void k_decoder(const unsigned short* __restrict__ zb,
                                                 float* __restrict__ recon) {
    int t = threadIdx.x;
    int wave = t >> 6, lane = t & 63;
    int i0 = blockIdx.y * 64 + (wave >> 1) * 32;
    int j0 = blockIdx.x * 64 + (wave & 1) * 32;
    int r = lane & 31, half = lane >> 5;
    int arow = i0 + r, brow = j0 + r;

    short8 zero8 = {0,0,0,0,0,0,0,0};
    short8 a[4], b[4];
    #pragma unroll
    for (int s = 0; s < 4; ++s) {
        a[s] = (arow < N_NODES) ? *(const short8*)(zb + (size_t)arow * H2F + s * 16 + half * 8)
                                : zero8;
        b[s] = (brow < N_NODES) ? *(const short8*)(zb + (size_t)brow * H2F + s * 16 + half * 8)
                                : zero8;
    }
    f32x16 acc;
    #pragma unroll
    for (int i = 0; i < 16; ++i) acc[i] = 0.f;
    #pragma unroll
    for (int s = 0; s < 4; ++s)
        acc = __builtin_amdgcn_mfma_f32_32x32x16_bf16(a[s], b[s], acc, 0, 0, 0);

    #pragma unroll
    for (int rg = 0; rg < 16; ++rg) {
        int row = i0 + (rg & 3) + 8 * (rg >> 2) + 4 * half;
        int col = j0 + r;
        if (row < N_NODES && col < N_NODES) {
            float sv = acc[rg];
            recon[(size_t)row * N_NODES + col] = 1.0f / (1.0f + __expf(-sv));
        }
    }
}

extern "C" void kernel_launch(void* const* d_in, const int* in_sizes, int n_in,
                              void* d_out, int out_size, void* d_ws, size_t ws_size,
                              hipStream_t stream) {
    int ix = -1, iW1 = -1, ib1 = -1, iW2 = -1, ib2 = -1, ic0 = -1, ic1 = -1, ic2 = -1;
    for (int i = 0; i < n_in; ++i) {
        int s = in_sizes[i];
        if      (s == N_NODES * IN_F) ix = i;
        else if (s == IN_F * H1F)     iW1 = i;
        else if (s == H1F)            ib1 = i;
        else if (s == H1F * H2F)      iW2 = i;
        else if (s == H2F)            ib2 = i;
        else if (s == N_EDGES) { if (ic0 < 0) ic0 = i; else if (ic1 < 0) ic1 = i; else ic2 = i; }
    }
    if (ix < 0 || iW1 < 0 || ib1 < 0 || iW2 < 0 || ib2 < 0 || ic0 < 0 || ic1 < 0 || ic2 < 0) {
        ix = 0; iW1 = 1; ib1 = 2; iW2 = 3; ib2 = 4; ic0 = 5; ic1 = 6; ic2 = 7;
    }
    const float* x  = (const float*)d_in[ix];
    const float* W1 = (const float*)d_in[iW1];
    const float* b1 = (const float*)d_in[ib1];
    const float* W2 = (const float*)d_in[iW2];
    const float* b2 = (const float*)d_in[ib2];
    const int*   c0  = (const int*)d_in[ic0];
    const int*   c1  = (const int*)d_in[ic1];
    const int*   c2  = (const int*)d_in[ic2];
    const float* c0f = (const float*)d_in[ic0];
    const float* c2f = (const float*)d_in[ic2];

    float* zout  = (float*)d_out;                        // z: 640000 fp32
    float* recon = zout + (size_t)N_NODES * H2F;         // recon: 1e8 fp32 (400 MB)
    unsigned short* zb = (unsigned short*)d_ws;          // 1.28 MB (decoder input)

    // Scratch inside fp32 recon region (dead before k_decoder overwrites it).
    char* scratch = (char*)recon;
    size_t o = 0;
    auto alloc = [&](size_t bytes) { size_t p = o; o += (bytes + 255) & ~(size_t)255; return p; };
    int*            deg     = (int*)           (scratch + alloc((size_t)N_NODES * 4));
    int*            off     = (int*)           (scratch + alloc((size_t)(N_NODES + 1) * 4));
    int*            cursor  = (int*)           (scratch + alloc((size_t)N_NODES * 4));
    int2*           ep      = (int2*)          (scratch + alloc((size_t)N_EDGES * 8));
    unsigned short* sup1b   = (unsigned short*)(scratch + alloc((size_t)N_NODES * H1F * 2));
    float*          h1      = (float*)         (scratch + alloc((size_t)N_NODES * H1F * 4));
    float*          sup2    = (float*)         (scratch + alloc((size_t)N_NODES * H2F * 4));
    unsigned short* W1t     = (unsigned short*)(scratch + alloc((size_t)IN_F * H1F * 2));
    unsigned short* W2t     = (unsigned short*)(scratch + alloc((size_t)H1F * H2F * 2));
    int*            partial = (int*)           (scratch + alloc(1024));
    int*            pex     = (int*)           (scratch + alloc(1024 + 4));

    // weight transpose (independent of CSR)
    k_wtrans<<<(IN_F * H1F + H1F * H2F + 255) / 256, 256, 0, stream>>>(W1, W2, W1t, W2t);

    // cooperative CSR build: one launch replaces memset+hist+scan+bucket
    {
        void* args[] = { (void*)&c0, (void*)&c1, (void*)&c2, (void*)&c0f, (void*)&c2f,
                         (void*)&deg, (void*)&off, (void*)&cursor, (void*)&ep,
                         (void*)&partial, (void*)&pex };
        hipLaunchCooperativeKernel((const void*)k_csr, dim3(256), dim3(256), args, 0, stream);
    }

    k_gemm1m<<<(N_NODES + 63) / 64, 256, 0, stream>>>(x, W1t, sup1b);
    k_agg1  <<<N_NODES, 256, 0, stream>>>(sup1b, off, ep, b1, h1);

    k_gemm2m<<<(N_NODES + 63) / 64, 256, 0, stream>>>(h1, W2t, sup2);
    k_agg2  <<<N_NODES, 64, 0, stream>>>(sup2, off, ep, b2, zout, zb);

    dim3 dgrid((N_NODES + 63) / 64, (N_NODES + 63) / 64);
    k_decoder<<<dgrid, 256, 0, stream>>>(zb, recon);
}

// Round 15
// 609.085 us; speedup vs baseline: 1.1985x; 1.1985x over previous
//
#include <hip/hip_runtime.h>

#define N_NODES 10000
#define N_EDGES 320000
#define IN_F    512
#define H1F     256
#define H2F     64

typedef __attribute__((ext_vector_type(8)))  short short8;   // 8 x bf16 (4 VGPRs)
typedef __attribute__((ext_vector_type(16))) float f32x16;   // MFMA 32x32 accumulator

__device__ __forceinline__ unsigned short f2bf(float f) {
    union { float fl; unsigned int i; } v; v.fl = f;
    unsigned int x = v.i;
    return (unsigned short)((x + 0x7fffu + ((x >> 16) & 1u)) >> 16);
}
__device__ __forceinline__ float bf2f(unsigned short u) {
    union { unsigned int i; float f; } v; v.i = ((unsigned int)u) << 16; return v.f;
}
// dict order (ew,src,dst): c0=float weight, int-reinterp never in [0,N_NODES)
// (only denormals); alpha order (dst,src,ew): c0=dst always is.
__device__ __forceinline__ bool edge_is_alpha(int a0) {
    return (unsigned)a0 < N_NODES;
}

// ---------- CSR build: histogram -> scan -> bucket (packed (src,w)) ----------
__global__ __launch_bounds__(256) void k_hist(const int* __restrict__ c0,
                                              const int* __restrict__ c2,
                                              int* __restrict__ deg) {
    int e = blockIdx.x * 256 + threadIdx.x;
    if (e >= N_EDGES) return;
    int a0 = c0[e];
    int dst = edge_is_alpha(a0) ? a0 : c2[e];
    if ((unsigned)dst < N_NODES) atomicAdd(&deg[dst], 1);
}

__global__ __launch_bounds__(1024) void k_scan(const int* __restrict__ deg,
                                               int* __restrict__ off,
                                               int* __restrict__ cursor) {
    __shared__ int part[1024];
    int t = threadIdx.x;
    const int chunk = (N_NODES + 1023) / 1024;  // 10
    int begin = t * chunk;
    int end = begin + chunk; if (end > N_NODES) end = N_NODES;
    if (begin > N_NODES) begin = N_NODES;
    int s = 0;
    for (int i = begin; i < end; ++i) s += deg[i];
    part[t] = s;
    __syncthreads();
    for (int o = 1; o < 1024; o <<= 1) {
        int v = (t >= o) ? part[t - o] : 0;
        __syncthreads();
        part[t] += v;
        __syncthreads();
    }
    int base = (t == 0) ? 0 : part[t - 1];
    for (int i = begin; i < end; ++i) {
        off[i] = base; cursor[i] = base; base += deg[i];
    }
    if (t == 1023) off[N_NODES] = part[1023];
}

__global__ __launch_bounds__(256) void k_bucket(const int* __restrict__ c0,
                                                const int* __restrict__ c1,
                                                const int* __restrict__ c2,
                                                const float* __restrict__ c0f,
                                                const float* __restrict__ c2f,
                                                int* __restrict__ cursor,
                                                int2* __restrict__ ep) {
    int e = blockIdx.x * 256 + threadIdx.x;
    if (e >= N_EDGES) return;
    int a0 = c0[e];
    bool alpha = edge_is_alpha(a0);
    int src = c1[e];
    int dst = alpha ? a0 : c2[e];
    float w = alpha ? c2f[e] : c0f[e];
    if ((unsigned)src >= N_NODES || (unsigned)dst >= N_NODES) return;
    int p = atomicAdd(&cursor[dst], 1);
    ep[p] = make_int2(src, __float_as_int(w));
}

// ---------- GEMM1: sup1b[10000,256] (bf16) = x @ W1, 8 nodes/block ----------
__global__ __launch_bounds__(256) void k_gemm1(const float* __restrict__ x,
                                               const float* __restrict__ W1,
                                               unsigned short* __restrict__ sup1b) {
    __shared__ float xs[IN_F][8];
    int nb = blockIdx.x * 8;
    int t = threadIdx.x;
    {
        int n  = t & 7;
        int k0 = (t >> 3) * 16;
        const float* xr = x + (size_t)(nb + n) * IN_F + k0;
        #pragma unroll
        for (int c = 0; c < 16; c += 4) {
            float4 v = *(const float4*)(xr + c);
            xs[k0 + c + 0][n] = v.x;
            xs[k0 + c + 1][n] = v.y;
            xs[k0 + c + 2][n] = v.z;
            xs[k0 + c + 3][n] = v.w;
        }
    }
    __syncthreads();
    int f = t;
    float acc[8] = {0.f,0.f,0.f,0.f,0.f,0.f,0.f,0.f};
    #pragma unroll 8
    for (int k = 0; k < IN_F; ++k) {
        float w = W1[(size_t)k * H1F + f];
        float4 a = *(const float4*)&xs[k][0];
        float4 b = *(const float4*)&xs[k][4];
        acc[0] += a.x * w; acc[1] += a.y * w; acc[2] += a.z * w; acc[3] += a.w * w;
        acc[4] += b.x * w; acc[5] += b.y * w; acc[6] += b.z * w; acc[7] += b.w * w;
    }
    #pragma unroll
    for (int n = 0; n < 8; ++n)
        sup1b[(size_t)(nb + n) * H1F + f] = f2bf(acc[n]);
}

// ---------- agg1: LDS-staged edges, 4-way unrolled independent gathers ----------
__global__ __launch_bounds__(256) void k_agg1(const unsigned short* __restrict__ sup1b,
                                              const int* __restrict__ off,
                                              const int2* __restrict__ ep,
                                              const float* __restrict__ b1,
                                              float* __restrict__ h1) {
    __shared__ int2 eds[256];
    int node = blockIdx.x;
    int f = threadIdx.x;
    int s = off[node], e = off[node + 1];
    float a0 = 0.f, a1 = 0.f, a2 = 0.f, a3 = 0.f;
    for (int base = s; base < e; base += 256) {
        int n = e - base; if (n > 256) n = 256;
        __syncthreads();
        if (f < n) eds[f] = ep[base + f];
        __syncthreads();
        int j = 0;
        for (; j + 4 <= n; j += 4) {
            int2 e0 = eds[j], e1 = eds[j+1], e2 = eds[j+2], e3 = eds[j+3];
            a0 += __int_as_float(e0.y) * bf2f(sup1b[(size_t)e0.x * H1F + f]);
            a1 += __int_as_float(e1.y) * bf2f(sup1b[(size_t)e1.x * H1F + f]);
            a2 += __int_as_float(e2.y) * bf2f(sup1b[(size_t)e2.x * H1F + f]);
            a3 += __int_as_float(e3.y) * bf2f(sup1b[(size_t)e3.x * H1F + f]);
        }
        for (; j < n; ++j) {
            int2 e0 = eds[j];
            a0 += __int_as_float(e0.y) * bf2f(sup1b[(size_t)e0.x * H1F + f]);
        }
    }
    float acc = (a0 + a1) + (a2 + a3);
    h1[(size_t)node * H1F + f] = fmaxf(acc + b1[f], 0.f);
}

// ---------- GEMM2: sup2[10000,64] = h1 @ W2, 4 nodes/block (fp32) ----------
__global__ __launch_bounds__(64) void k_gemm2(const float* __restrict__ h1,
                                              const float* __restrict__ W2,
                                              float* __restrict__ sup2) {
    __shared__ float hs[H1F][4];
    int nb = blockIdx.x * 4;
    int t = threadIdx.x;
    {
        int n  = t & 3;
        int k0 = (t >> 2) * 16;
        const float* hr = h1 + (size_t)(nb + n) * H1F + k0;
        #pragma unroll
        for (int c = 0; c < 16; c += 4) {
            float4 v = *(const float4*)(hr + c);
            hs[k0 + c + 0][n] = v.x;
            hs[k0 + c + 1][n] = v.y;
            hs[k0 + c + 2][n] = v.z;
            hs[k0 + c + 3][n] = v.w;
        }
    }
    __syncthreads();
    int f = t;
    float acc[4] = {0.f,0.f,0.f,0.f};
    #pragma unroll 8
    for (int k = 0; k < H1F; ++k) {
        float w = W2[(size_t)k * H2F + f];
        float4 a = *(const float4*)&hs[k][0];
        acc[0] += a.x * w; acc[1] += a.y * w; acc[2] += a.z * w; acc[3] += a.w * w;
    }
    #pragma unroll
    for (int n = 0; n < 4; ++n)
        sup2[(size_t)(nb + n) * H2F + f] = acc[n];
}

// ---------- agg2: LDS-staged, unrolled; z fp32 (d_out) + bf16 zb (ws) ----------
__global__ __launch_bounds__(64) void k_agg2(const float* __restrict__ sup2,
                                             const int* __restrict__ off,
                                             const int2* __restrict__ ep,
                                             const float* __restrict__ b2,
                                             float* __restrict__ zout,
                                             unsigned short* __restrict__ zb) {
    __shared__ int2 eds[64];
    int node = blockIdx.x;
    int f = threadIdx.x;
    int s = off[node], e = off[node + 1];
    float a0 = 0.f, a1 = 0.f, a2 = 0.f, a3 = 0.f;
    for (int base = s; base < e; base += 64) {
        int n = e - base; if (n > 64) n = 64;
        __syncthreads();
        if (f < n) eds[f] = ep[base + f];
        __syncthreads();
        int j = 0;
        for (; j + 4 <= n; j += 4) {
            int2 e0 = eds[j], e1 = eds[j+1], e2 = eds[j+2], e3 = eds[j+3];
            a0 += __int_as_float(e0.y) * sup2[(size_t)e0.x * H2F + f];
            a1 += __int_as_float(e1.y) * sup2[(size_t)e1.x * H2F + f];
            a2 += __int_as_float(e2.y) * sup2[(size_t)e2.x * H2F + f];
            a3 += __int_as_float(e3.y) * sup2[(size_t)e3.x * H2F + f];
        }
        for (; j < n; ++j) {
            int2 e0 = eds[j];
            a0 += __int_as_float(e0.y) * sup2[(size_t)e0.x * H2F + f];
        }
    }
    float acc = (a0 + a1) + (a2 + a3);
    acc = fmaxf(acc + b2[f], 0.f);
    zout[(size_t)node * H2F + f] = acc;
    zb[(size_t)node * H2F + f] = f2bf(acc);
}

// ---------- decoder: symmetric Gram — compute upper-triangle tiles once, ----------
// sigmoid once, stage in LDS, store straight + transposed (mirror).
// C/D layout (HW-verified): col = lane&31, row = (reg&3) + 8*(reg>>2) + 4*(lane>>5)
__global__ __launch_bounds__(256) void k_decoder(const unsigned short* __restrict__ zb,
                                                 float* __restrict__ recon) {
    int bi = blockIdx.y, bj = blockIdx.x;
    if (bj < bi) return;                      // mirror writes cover the lower triangle
    __shared__ float Cs[64][65];              // +1 pad: transposed reads conflict-free
    int t = threadIdx.x;
    int wave = t >> 6, lane = t & 63;
    int wi = (wave >> 1) * 32, wj = (wave & 1) * 32;
    int i0 = bi * 64 + wi, j0 = bj * 64 + wj;
    int r = lane & 31, half = lane >> 5;
    int arow = i0 + r, brow = j0 + r;

    short8 zero8 = {0,0,0,0,0,0,0,0};
    short8 a[4], b[4];
    #pragma unroll
    for (int s = 0; s < 4; ++s) {
        a[s] = (arow < N_NODES) ? *(const short8*)(zb + (size_t)arow * H2F + s * 16 + half * 8)
                                : zero8;
        b[s] = (brow < N_NODES) ? *(const short8*)(zb + (size_t)brow * H2F + s * 16 + half * 8)
                                : zero8;
    }
    f32x16 acc;
    #pragma unroll
    for (int i = 0; i < 16; ++i) acc[i] = 0.f;
    #pragma unroll
    for (int s = 0; s < 4; ++s)
        acc = __builtin_amdgcn_mfma_f32_32x32x16_bf16(a[s], b[s], acc, 0, 0, 0);

    // sigmoid once, into LDS tile
    #pragma unroll
    for (int rg = 0; rg < 16; ++rg) {
        int lr = wi + (rg & 3) + 8 * (rg >> 2) + 4 * half;
        int lc = wj + r;
        Cs[lr][lc] = 1.0f / (1.0f + __expf(-acc[rg]));
    }
    __syncthreads();

    // straight write: 4 reps, thread t covers tile elements [p*1024 + t*4 ..+3]
    #pragma unroll
    for (int p = 0; p < 4; ++p) {
        int e = p * 1024 + t * 4;
        int lr = e >> 6, lc = e & 63;
        int grow = bi * 64 + lr, gcol = bj * 64 + lc;
        if (grow < N_NODES) {
            float4 v = *(const float4*)&Cs[lr][lc];
            size_t base = (size_t)grow * N_NODES + gcol;
            if (gcol + 4 <= N_NODES) *(float4*)&recon[base] = v;
            else {
                const float* vp = &v.x;
                for (int k = 0; k < 4; ++k)
                    if (gcol + k < N_NODES) recon[base + k] = vp[k];
            }
        }
    }
    // mirror (transposed) write into block (bj, bi); diagonal written once above
    if (bi != bj) {
        #pragma unroll
        for (int p = 0; p < 4; ++p) {
            int e = p * 1024 + t * 4;
            int lr = e >> 6, lc = e & 63;
            int grow = bj * 64 + lr, gcol = bi * 64 + lc;
            if (grow < N_NODES) {
                float4 v = make_float4(Cs[lc][lr], Cs[lc+1][lr], Cs[lc+2][lr], Cs[lc+3][lr]);
                size_t base = (size_t)grow * N_NODES + gcol;
                if (gcol + 4 <= N_NODES) *(float4*)&recon[base] = v;
                else {
                    const float* vp = &v.x;
                    for (int k = 0; k < 4; ++k)
                        if (gcol + k < N_NODES) recon[base + k] = vp[k];
                }
            }
        }
    }
}

extern "C" void kernel_launch(void* const* d_in, const int* in_sizes, int n_in,
                              void* d_out, int out_size, void* d_ws, size_t ws_size,
                              hipStream_t stream) {
    int ix = -1, iW1 = -1, ib1 = -1, iW2 = -1, ib2 = -1, ic0 = -1, ic1 = -1, ic2 = -1;
    for (int i = 0; i < n_in; ++i) {
        int s = in_sizes[i];
        if      (s == N_NODES * IN_F) ix = i;
        else if (s == IN_F * H1F)     iW1 = i;
        else if (s == H1F)            ib1 = i;
        else if (s == H1F * H2F)      iW2 = i;
        else if (s == H2F)            ib2 = i;
        else if (s == N_EDGES) { if (ic0 < 0) ic0 = i; else if (ic1 < 0) ic1 = i; else ic2 = i; }
    }
    if (ix < 0 || iW1 < 0 || ib1 < 0 || iW2 < 0 || ib2 < 0 || ic0 < 0 || ic1 < 0 || ic2 < 0) {
        ix = 0; iW1 = 1; ib1 = 2; iW2 = 3; ib2 = 4; ic0 = 5; ic1 = 6; ic2 = 7;
    }
    const float* x  = (const float*)d_in[ix];
    const float* W1 = (const float*)d_in[iW1];
    const float* b1 = (const float*)d_in[ib1];
    const float* W2 = (const float*)d_in[iW2];
    const float* b2 = (const float*)d_in[ib2];
    const int*   c0  = (const int*)d_in[ic0];
    const int*   c1  = (const int*)d_in[ic1];
    const int*   c2  = (const int*)d_in[ic2];
    const float* c0f = (const float*)d_in[ic0];
    const float* c2f = (const float*)d_in[ic2];

    float* zout  = (float*)d_out;                        // z: 640000 fp32
    float* recon = zout + (size_t)N_NODES * H2F;         // recon: 1e8 fp32 (400 MB)
    unsigned short* zb = (unsigned short*)d_ws;          // 1.28 MB (decoder input)

    // Scratch inside fp32 recon region (dead before k_decoder overwrites it).
    char* scratch = (char*)recon;
    size_t o = 0;
    auto alloc = [&](size_t bytes) { size_t p = o; o += (bytes + 255) & ~(size_t)255; return p; };
    int*            deg    = (int*)           (scratch + alloc((size_t)N_NODES * 4));
    int*            off    = (int*)           (scratch + alloc((size_t)(N_NODES + 1) * 4));
    int*            cursor = (int*)           (scratch + alloc((size_t)N_NODES * 4));
    int2*           ep     = (int2*)          (scratch + alloc((size_t)N_EDGES * 8));
    unsigned short* sup1b  = (unsigned short*)(scratch + alloc((size_t)N_NODES * H1F * 2));
    float*          h1     = (float*)         (scratch + alloc((size_t)N_NODES * H1F * 4));
    float*          sup2   = (float*)         (scratch + alloc((size_t)N_NODES * H2F * 4));

    hipMemsetAsync(deg, 0, (size_t)N_NODES * 4, stream);
    k_hist  <<<(N_EDGES + 255) / 256, 256, 0, stream>>>(c0, c2, deg);
    k_scan  <<<1, 1024, 0, stream>>>(deg, off, cursor);
    k_bucket<<<(N_EDGES + 255) / 256, 256, 0, stream>>>(c0, c1, c2, c0f, c2f, cursor, ep);

    k_gemm1<<<N_NODES / 8, 256, 0, stream>>>(x, W1, sup1b);
    k_agg1 <<<N_NODES, 256, 0, stream>>>(sup1b, off, ep, b1, h1);

    k_gemm2<<<N_NODES / 4, 64, 0, stream>>>(h1, W2, sup2);
    k_agg2 <<<N_NODES, 64, 0, stream>>>(sup2, off, ep, b2, zout, zb);

    dim3 dgrid((N_NODES + 63) / 64, (N_NODES + 63) / 64);
    k_decoder<<<dgrid, 256, 0, stream>>>(zb, recon);
}